// Round 6
// baseline (3398.723 us; speedup 1.0000x reference)
//
#include <hip/hip_runtime.h>
#include <hip/hip_bf16.h>

// LGA3D2: out = A_g(A_g(x)); A_g is a 5x5 spatial x 3-depth guided aggregation.
// out[b,c,d,h,w] = sum_{i,j in 5x5, k in 0..2} g[b,(i*5+j)*3+k,h,w] * x[b,c,d+k-1,h+i-2,w+j-2]
// x: [B,C,D,H,W] fp32, g: [B,75,H,W] fp32.
//
// R6: direct-global register-window form (R2 structure) with occupancy fixed.
// Block = (b,c,h): 512 threads = 8 waves x 64 lanes; wave dg owns depths
// dg*6..dg*6+5 (full D=48 per block), lane owns w = 4*lane..4*lane+3.
// Per (i, depth-row): 3 shifted float4 loads give a 12-float register window
// (the 3 shifts of each row self-serve from L1 within the wave); 15 guidance
// float4s live in registers per i-tap, reused across 8 depth rows (scatter
// form: row d feeds acc depths d+1,d,d-1). No LDS -> zero bank conflicts.
// DPG=6 keeps live state ~118 VGPR; __launch_bounds__(512,4) pins the cap at
// 128 (4 waves/SIMD) WITHOUT spilling (R3 lesson: only cap near live-count).

constexpr int RAD = 2;
constexpr int BB = 2, CC = 16, DD = 48, HH = 128, WW = 256;
constexpr int GG = 75;
constexpr int PLANE = HH * WW;

constexpr int WPT = 4;             // outputs per lane along W
constexpr int NWT = WW / WPT;      // 64 lanes span W
constexpr int DPG = 6;             // depths per wave
constexpr int NWAVES = 8;          // 8 waves cover D=48
constexpr int TPB = 64 * NWAVES;   // 512

__device__ __forceinline__ float bf2f(unsigned short u) {
  union { unsigned int i; float f; } c; c.i = ((unsigned int)u) << 16; return c.f;
}
__device__ __forceinline__ unsigned short f2bf(float f) {
  union { float f; unsigned int i; } c; c.f = f;
  unsigned int r = c.i + 0x7FFFu + ((c.i >> 16) & 1u);  // round-nearest-even
  return (unsigned short)(r >> 16);
}

__device__ __forceinline__ void load4(float* v, const float* p, int off) {
  const float4 t = *reinterpret_cast<const float4*>(p + off);
  v[0] = t.x; v[1] = t.y; v[2] = t.z; v[3] = t.w;
}
__device__ __forceinline__ void load4(float* v, const __hip_bfloat16* p, int off) {
  const ushort4 t = *reinterpret_cast<const ushort4*>(p + off);
  v[0] = bf2f(t.x); v[1] = bf2f(t.y); v[2] = bf2f(t.z); v[3] = bf2f(t.w);
}
__device__ __forceinline__ void store4(float* p, int off, const float* v) {
  float4 t; t.x = v[0]; t.y = v[1]; t.z = v[2]; t.w = v[3];
  *reinterpret_cast<float4*>(p + off) = t;
}
__device__ __forceinline__ void store4(__hip_bfloat16* p, int off, const float* v) {
  ushort4 t; t.x = f2bf(v[0]); t.y = f2bf(v[1]); t.z = f2bf(v[2]); t.w = f2bf(v[3]);
  *reinterpret_cast<ushort4*>(p + off) = t;
}

template <typename IT, typename OT>
__global__ __launch_bounds__(TPB, 4) void lga_pass(const IT* __restrict__ x,
                                                   const float* __restrict__ g,
                                                   OT* __restrict__ out) {
  // XCD-bijective swizzle (nwg=4096, div by 8), h fastest within an XCD
  // chunk so the 5-row h-halo is served by that XCD's L2.
  constexpr int NWG = BB * CC * HH;   // 4096
  const int bx = blockIdx.x;
  const int lid = (bx & 7) * (NWG >> 3) + (bx >> 3);
  const int h = lid % HH;
  const int c = (lid / HH) % CC;
  const int b = lid / (HH * CC);

  const int lane = threadIdx.x & 63;
  const int dg = threadIdx.x >> 6;    // wave index = depth group (uniform)
  const int w0 = lane * WPT;
  const int d0 = dg * DPG;
  const bool wlo = (lane > 0);
  const bool whi = (lane < NWT - 1);

  float acc[DPG][WPT];
#pragma unroll
  for (int a = 0; a < DPG; ++a)
#pragma unroll
    for (int q = 0; q < WPT; ++q) acc[a][q] = 0.f;

  // 32-bit element offsets from SGPR-uniform bases (max index < 2^31).
  const IT* xb = x + (size_t)(b * CC + c) * DD * PLANE;
  const float* gb = g + (size_t)b * GG * PLANE;
  const int gbase = h * WW + w0;

  for (int i = 0; i < 5; ++i) {
    const int hr = h + i - RAD;
    if (hr < 0 || hr >= HH) continue;       // block-uniform (zero pad)

    // 15 guidance channels for this i-row, float4 at (h,w0); registers,
    // reused across all 8 depth rows below.
    float gr[15][WPT];
#pragma unroll
    for (int t = 0; t < 15; ++t) load4(gr[t], gb, (i * 15 + t) * PLANE + gbase);

    const int rowb = hr * WW + w0;

#pragma unroll
    for (int a = -1; a <= DPG; ++a) {       // x depth rows d0-1 .. d0+6
      // Depth zero-pad (wave-uniform): only edge waves clip.
      bool dok = true;
      if (a == -1)  dok = (dg > 0);
      if (a == DPG) dok = (dg < NWAVES - 1);

      // 12-float register window covering w = w0-4 .. w0+7
      float v[12];
      if (dok) {
        const int roff = (d0 + a) * PLANE + rowb;
        if (wlo) load4(v + 0, xb, roff - 4);
        else { v[0] = v[1] = v[2] = v[3] = 0.f; }
        load4(v + 4, xb, roff);
        if (whi) load4(v + 8, xb, roff + 4);
        else { v[8] = v[9] = v[10] = v[11] = 0.f; }
      } else {
#pragma unroll
        for (int t = 0; t < 12; ++t) v[t] = 0.f;
      }

      // scatter: x depth d0+a feeds acc[a+1-k] with weight channel j*3+k
#pragma unroll
      for (int j = 0; j < 5; ++j)
#pragma unroll
        for (int k = 0; k < 3; ++k) {
          const int ai = a + 1 - k;         // compile-time
          if (ai < 0 || ai >= DPG) continue;
#pragma unroll
          for (int q = 0; q < WPT; ++q)
            acc[ai][q] = fmaf(gr[j * 3 + k][q], v[q + j + 2], acc[ai][q]);
        }
    }
  }

  OT* ob = out + (size_t)(b * CC + c) * DD * PLANE;
  const int obase = d0 * PLANE + h * WW + w0;
#pragma unroll
  for (int ai = 0; ai < DPG; ++ai) store4(ob, obase + ai * PLANE, acc[ai]);
}

extern "C" void kernel_launch(void* const* d_in, const int* in_sizes, int n_in,
                              void* d_out, int out_size, void* d_ws, size_t ws_size,
                              hipStream_t stream) {
  const float* x = (const float*)d_in[0];
  const float* g = (const float*)d_in[1];
  float* out = (float*)d_out;

  const size_t elems = (size_t)BB * CC * DD * HH * WW;
  const dim3 grid(BB * CC * HH);   // 4096
  const dim3 block(TPB);           // 512

  if (ws_size >= elems * sizeof(float)) {
    float* y = (float*)d_ws;
    lga_pass<float, float><<<grid, block, 0, stream>>>(x, g, y);
    lga_pass<float, float><<<grid, block, 0, stream>>>(y, g, out);
  } else {
    __hip_bfloat16* y = (__hip_bfloat16*)d_ws;
    lga_pass<float, __hip_bfloat16><<<grid, block, 0, stream>>>(x, g, y);
    lga_pass<__hip_bfloat16, float><<<grid, block, 0, stream>>>(y, g, out);
  }
}

// Round 7
// 498.932 us; speedup vs baseline: 6.8120x; 6.8120x over previous
//
#include <hip/hip_runtime.h>
#include <hip/hip_bf16.h>

// LGA3D2: out = A_g(A_g(x)); A_g is a 5x5 spatial x 3-depth guided aggregation.
// out[b,c,d,h,w] = sum_{i,j in 5x5, k in 0..2} g[b,(i*5+j)*3+k,h,w] * x[b,c,d+k-1,h+i-2,w+j-2]
// x: [B,C,D,H,W] fp32, g: [B,75,H,W] fp32.
//
// R7: R5's LDS-staged double-buffered structure with the two wounds fixed:
//  - __launch_bounds__(256,1): relax regalloc occupancy target -> no spills
//    (R3/R5/R6 lesson: heuristic clamps to 64 VGPR and spills ~90+ live).
//  - Padded LDS layout: dword w' at position w' + (w'>>5). All window reads
//    are ds_read_b32 with <=2 lanes/bank (free). Staging is reg-staged
//    (global dwordx4 issued early -> ds_write_b32 x4 after compute), since
//    global_load_lds can't write a padded layout.
// Block = (b,c,dch=16 depths,h); 4 waves x 64 lanes; lane owns 4w x 4d
// outputs. Scatter over depth: slab row d feeds acc[d+1-k], k=0..2.

constexpr int RAD = 2;
constexpr int BB = 2, CC = 16, DD = 48, HH = 128, WW = 256;
constexpr int GG = 75;
constexpr int PLANE = HH * WW;

constexpr int WPT = 4;            // outputs per lane along W
constexpr int DPG = 4;            // depths per wave-lane
constexpr int NWV = 4;            // waves per block
constexpr int DCHUNK = 16;        // depths per block
constexpr int NCH = DD / DCHUNK;  // 3
constexpr int SROWS = DCHUNK + 2; // 18 slab rows (d-1 .. d+16)
constexpr int RPAD = 268;         // 260 logical dwords (w'=w+2) + 8 bank pads

using uint = unsigned int;

__device__ __forceinline__ float lo16(uint u) { union {uint i; float f;} c; c.i = u << 16; return c.f; }
__device__ __forceinline__ float hi16(uint u) { union {uint i; float f;} c; c.i = u & 0xFFFF0000u; return c.f; }
__device__ __forceinline__ unsigned short f2bf(float f) {
  union { float f; uint i; } c; c.f = f;
  uint r = c.i + 0x7FFFu + ((c.i >> 16) & 1u);  // round-nearest-even
  return (unsigned short)(r >> 16);
}
__device__ __forceinline__ void store4(float* p, int off, const float* v) {
  float4 t; t.x = v[0]; t.y = v[1]; t.z = v[2]; t.w = v[3];
  *reinterpret_cast<float4*>(p + off) = t;
}
__device__ __forceinline__ void store4(__hip_bfloat16* p, int off, const float* v) {
  ushort4 t; t.x = f2bf(v[0]); t.y = f2bf(v[1]); t.z = f2bf(v[2]); t.w = f2bf(v[3]);
  *reinterpret_cast<ushort4*>(p + off) = t;
}

template <typename IT, typename OT>
__global__ __launch_bounds__(256, 1) void lga_pass(const IT* __restrict__ x,
                                                   const float* __restrict__ g,
                                                   OT* __restrict__ out) {
  __shared__ float lds[2][SROWS][RPAD];   // 38592 B -> 4 blocks/CU

  // XCD-bijective swizzle. Logical order: dch fastest (g-row + depth-border
  // reuse), then h (x h-halo reuse), then c, b.
  constexpr int NWG = BB * CC * NCH * HH;   // 12288
  const int bx = blockIdx.x;
  const int lid = (bx & 7) * (NWG >> 3) + (bx >> 3);
  const int dch = lid % NCH;
  const int h   = (lid / NCH) % HH;
  const int c   = (lid / (NCH * HH)) % CC;
  const int b   =  lid / (NCH * HH * CC);

  const int tid = threadIdx.x;
  const int lane = tid & 63;
  const int dg = tid >> 6;                 // wave index (uniform)
  const int w0 = lane * WPT;
  const int d0 = dch * DCHUNK + dg * DPG;

  const IT* xb = x + (size_t)(b * CC + c) * DD * PLANE;
  const float* gb = g + (size_t)b * GG * PLANE;
  const int gbase = h * WW + w0;

  // ---- zero init: w-pad dwords (w'=0,1,258,259 -> p=0,1,266,267) all rows
  //      both bufs; full rows for out-of-range depths (never staged).
  if (tid < 2 * SROWS) {
    const int buf = tid / SROWS, s = tid % SROWS;
    lds[buf][s][0] = 0.f; lds[buf][s][1] = 0.f;
    lds[buf][s][266] = 0.f; lds[buf][s][267] = 0.f;
  }
  if (dch == 0)
    for (int idx = tid; idx < 2 * RPAD; idx += 256)
      lds[idx / RPAD][0][idx % RPAD] = 0.f;
  if (dch == NCH - 1)
    for (int idx = tid; idx < 2 * RPAD; idx += 256)
      lds[idx / RPAD][SROWS - 1][idx % RPAD] = 0.f;

  float acc[DPG][WPT];
#pragma unroll
  for (int a = 0; a < DPG; ++a)
#pragma unroll
    for (int q = 0; q < WPT; ++q) acc[a][q] = 0.f;

  const int ilo = (h >= RAD) ? 0 : RAD - h;
  const int him = HH - 1 + RAD - h;
  const int ihi = (him < 4) ? him : 4;

  // Stage registers: wave dg owns slab rows s = dg, dg+4, ... (<=5 rows).
  uint4 sr[5];

  auto stage_load = [&](int i) {
    const int hr = h + i - RAD;
#pragma unroll
    for (int t = 0; t < 5; ++t) {
      const int s = dg + NWV * t;
      if (s < SROWS &&
          !(s == 0 && dch == 0) && !(s == SROWS - 1 && dch == NCH - 1)) {
        const int dd = dch * DCHUNK + s - 1;
        if constexpr (sizeof(IT) == 4) {
          sr[t] = *reinterpret_cast<const uint4*>(xb + (size_t)dd * PLANE + hr * WW + w0);
        } else {
          const uint2 u = *reinterpret_cast<const uint2*>(xb + (size_t)dd * PLANE + hr * WW + w0);
          sr[t].x = u.x; sr[t].y = u.y;
        }
      }
    }
  };

  auto stage_write = [&](int buf) {
#pragma unroll
    for (int t = 0; t < 5; ++t) {
      const int s = dg + NWV * t;
      if (s < SROWS &&
          !(s == 0 && dch == 0) && !(s == SROWS - 1 && dch == NCH - 1)) {
        float v0, v1, v2, v3;
        if constexpr (sizeof(IT) == 4) {
          v0 = __uint_as_float(sr[t].x); v1 = __uint_as_float(sr[t].y);
          v2 = __uint_as_float(sr[t].z); v3 = __uint_as_float(sr[t].w);
        } else {
          v0 = lo16(sr[t].x); v1 = hi16(sr[t].x);
          v2 = lo16(sr[t].y); v3 = hi16(sr[t].y);
        }
        float* row = lds[buf][s];
        const int wp = w0 + 2;            // logical w' of first staged dword
        row[(wp + 0) + ((wp + 0) >> 5)] = v0;
        row[(wp + 1) + ((wp + 1) >> 5)] = v1;
        row[(wp + 2) + ((wp + 2) >> 5)] = v2;
        row[(wp + 3) + ((wp + 3) >> 5)] = v3;
      }
    }
  };

  int cur = 0;
  stage_load(ilo);
  stage_write(0);        // compiler emits vmcnt wait before first sr use
  __syncthreads();

  for (int ii = ilo; ii <= ihi; ++ii) {
    // Guidance for this i-tap FIRST (oldest vmem -> waiting on gr leaves the
    // younger stage loads in flight).
    float gr[15][WPT];
#pragma unroll
    for (int t = 0; t < 15; ++t) {
      const float4 t4 = *reinterpret_cast<const float4*>(
          gb + (size_t)(ii * 15 + t) * PLANE + gbase);
      gr[t][0] = t4.x; gr[t][1] = t4.y; gr[t][2] = t4.z; gr[t][3] = t4.w;
    }
    if (ii < ihi) stage_load(ii + 1);     // async under compute

    const float (*bufr)[RPAD] = lds[cur];
#pragma unroll
    for (int a = -1; a <= DPG; ++a) {     // slab rows d0-1 .. d0+4
      const int s = dg * DPG + a + 1;     // wave-uniform, in [0,17]
      const float* row = bufr[s];
      float v[8];                         // x at w = w0-2 .. w0+5
#pragma unroll
      for (int t = 0; t < 8; ++t) {
        const int wp = w0 + t;            // w' = (w0-2+t)+2
        v[t] = row[wp + (wp >> 5)];
      }
      // scatter: row d0+a feeds acc[a+1-k] with weight channel j*3+k
#pragma unroll
      for (int k = 0; k < 3; ++k) {
        const int ai = a + 1 - k;
        if (ai < 0 || ai >= DPG) continue;  // compile-time
#pragma unroll
        for (int j = 0; j < 5; ++j)
#pragma unroll
          for (int q = 0; q < WPT; ++q)
            acc[ai][q] = fmaf(gr[j * 3 + k][q], v[q + j], acc[ai][q]);
      }
    }
    if (ii < ihi) stage_write(cur ^ 1);   // vmcnt(0) lands after compute
    __syncthreads();
    cur ^= 1;
  }

  OT* ob = out + (size_t)(b * CC + c) * DD * PLANE;
  const int obase = d0 * PLANE + h * WW + w0;
#pragma unroll
  for (int ai = 0; ai < DPG; ++ai) store4(ob, obase + ai * PLANE, acc[ai]);
}

extern "C" void kernel_launch(void* const* d_in, const int* in_sizes, int n_in,
                              void* d_out, int out_size, void* d_ws, size_t ws_size,
                              hipStream_t stream) {
  const float* x = (const float*)d_in[0];
  const float* g = (const float*)d_in[1];
  float* out = (float*)d_out;

  const size_t elems = (size_t)BB * CC * DD * HH * WW;
  const dim3 grid(BB * CC * NCH * HH);   // 12288
  const dim3 block(64 * NWV);            // 256

  if (ws_size >= elems * sizeof(float)) {
    float* y = (float*)d_ws;
    lga_pass<float, float><<<grid, block, 0, stream>>>(x, g, y);
    lga_pass<float, float><<<grid, block, 0, stream>>>(y, g, out);
  } else {
    __hip_bfloat16* y = (__hip_bfloat16*)d_ws;
    lga_pass<float, __hip_bfloat16><<<grid, block, 0, stream>>>(x, g, y);
    lga_pass<__hip_bfloat16, float><<<grid, block, 0, stream>>>(y, g, out);
  }
}